// Round 1
// baseline (897.518 us; speedup 1.0000x reference)
//
#include <hip/hip_runtime.h>
#include <math.h>
#include <stdint.h>

#define HW 512
#define NACT 30

struct Maps {
    int src_i[64];
    int src_j[64];
    int mask[64];
    int aidx[64];
    int act_k[NACT];
};

static Maps make_maps() {
    Maps m;
    for (int k = 0; k < 64; k++) { m.src_i[k]=0; m.src_j[k]=0; m.mask[k]=0; m.aidx[k]=-1; }
    for (int i = 1; i <= 8; i++)
        for (int j = 1; j <= 8; j++) {
            int k = i*j-1;
            m.src_i[k]=i-1; m.src_j[k]=j-1; m.mask[k]=1;
        }
    int cnt=0;
    for (int k=0;k<64;k++) if (m.mask[k]) { m.aidx[k]=cnt; if (cnt < NACT) m.act_k[cnt]=k; cnt++; }
    return m;
}

// ---------------- K1: per-patch means fg  (8,32,64 patches of 64x64) -------------
__global__ __launch_bounds__(256) void k_fg(const float* __restrict__ x, float* __restrict__ fgw) {
    int blk = blockIdx.x;            // ((b*32 + c)*64 + k)
    int k = blk & 63;
    int bc = blk >> 6;
    int c = bc & 31;
    int b = bc >> 5;
    int pi = k >> 3, pj = k & 7;
    const float* xp = x + (size_t)(b*32+c)*HW*HW;
    int t = threadIdx.x;
    float s = 0.f;
    #pragma unroll
    for (int ii = 0; ii < 4; ii++) {
        int idx4 = t + 256*ii;          // float4 index within patch, 0..1023
        int y = idx4 >> 4;
        int xx = (idx4 & 15) * 4;
        float4 v = *(const float4*)(xp + (size_t)(pi*64 + y)*HW + pj*64 + xx);
        s += v.x + v.y + v.z + v.w;
    }
    for (int off = 32; off > 0; off >>= 1) s += __shfl_down(s, off);
    __shared__ float p[4];
    if ((t & 63) == 0) p[t >> 6] = s;
    __syncthreads();
    if (t == 0) {
        float tot = p[0]+p[1]+p[2]+p[3];
        fgw[(b*64 + k)*32 + c] = tot * (1.0f/4096.0f);
    }
}

// ---------------- K2: tiny gating MLP -> g (8,64,32) ------------------------------
__global__ void k_g(const float* __restrict__ fgw,
                    const float* __restrict__ w12a, const float* __restrict__ b12a,
                    const float* __restrict__ w12b, const float* __restrict__ b12b,
                    const float* __restrict__ w12c, const float* __restrict__ b12c,
                    float* __restrict__ g) {
    int b = blockIdx.x;
    int c = threadIdx.x;
    if (c >= 32) return;
    float fg[64];
    #pragma unroll
    for (int k = 0; k < 64; k++) fg[k] = fgw[(b*64+k)*32 + c];
    float g1[8], g2[8];
    #pragma unroll
    for (int o = 0; o < 8; o++) {
        float v = b12a[o];
        #pragma unroll
        for (int k2 = 0; k2 < 64; k2++) v += w12a[o*64+k2]*fg[k2];
        g1[o] = fmaxf(v, 0.f);
    }
    #pragma unroll
    for (int o = 0; o < 8; o++) {
        float v = b12b[o];
        #pragma unroll
        for (int k2 = 0; k2 < 8; k2++) v += w12b[o*8+k2]*g1[k2];
        g2[o] = fmaxf(v, 0.f);
    }
    for (int o = 0; o < 64; o++) {
        float v = b12c[o];
        #pragma unroll
        for (int k2 = 0; k2 < 8; k2++) v += w12c[o*8+k2]*g2[k2];
        g[(b*64+o)*32 + c] = 1.f / (1.f + expf(-v));
    }
}

// ---------------- K3: per-patch 3x3 SAME conv + relu -> B (active blocks only) ----
__global__ __launch_bounds__(256) void k_conv(
        const float* __restrict__ x, const float* __restrict__ w30,
        const float* __restrict__ b30, float* __restrict__ B, Maps m) {
    int blk = blockIdx.x;         // b*30 + a
    int rt = blockIdx.y;          // 0..3 row tile of 16
    int a = blk % NACT, b = blk / NACT;
    int k = m.act_k[a];
    int spi = m.src_i[k], spj = m.src_j[k];
    int r0 = rt*16;

    __shared__ float wl[8*32*9];
    __shared__ float xs[8*18*66];   // [cc][row(18)][col(66)]

    int t = threadIdx.x;
    for (int idx = t; idx < 2304; idx += 256) wl[idx] = w30[idx];

    int col = t & 63, tl = t >> 6;
    float acc[4][8];
    #pragma unroll
    for (int rr=0; rr<4; rr++)
        #pragma unroll
        for (int n=0;n<8;n++) acc[rr][n]=0.f;

    const float* xb = x + (size_t)b*32*HW*HW;

    for (int c0 = 0; c0 < 32; c0 += 8) {
        __syncthreads();
        for (int idx = t; idx < 8*18*66; idx += 256) {
            int cc = idx / (18*66);
            int rem = idx - cc*(18*66);
            int r = rem / 66;
            int ccol = rem - r*66;
            int pr = r0 - 1 + r;
            int pc = ccol - 1;
            float v = 0.f;
            if (pr >= 0 && pr < 64 && pc >= 0 && pc < 64)
                v = xb[(size_t)(c0+cc)*HW*HW + (size_t)(spi*64+pr)*HW + spj*64 + pc];
            xs[idx] = v;
        }
        __syncthreads();
        for (int cc = 0; cc < 8; cc++) {
            #pragma unroll
            for (int dy = 0; dy < 3; dy++) {
                #pragma unroll
                for (int dx = 0; dx < 3; dx++) {
                    float w[8];
                    #pragma unroll
                    for (int n = 0; n < 8; n++)
                        w[n] = wl[(n*32 + c0+cc)*9 + dy*3 + dx];
                    #pragma unroll
                    for (int rr = 0; rr < 4; rr++) {
                        float xv = xs[cc*1188 + (tl + 4*rr + dy)*66 + col + dx];
                        #pragma unroll
                        for (int n = 0; n < 8; n++)
                            acc[rr][n] = fmaf(xv, w[n], acc[rr][n]);
                    }
                }
            }
        }
    }
    float* Bp = B + (size_t)(b*NACT+a)*8*4096;
    #pragma unroll
    for (int rr=0; rr<4; rr++) {
        int y = r0 + tl + 4*rr;
        #pragma unroll
        for (int n=0;n<8;n++)
            Bp[n*4096 + y*64 + col] = fmaxf(acc[rr][n] + b30[n], 0.f);
    }
}

// ---------------- K4: fs2 = B @ fs^T (8x32 over L=4096) + fused fs3/fs5 ----------
__global__ __launch_bounds__(256) void k_fs2(
        const float* __restrict__ x, const float* __restrict__ B,
        const float* __restrict__ w11, const float* __restrict__ b11,
        const float* __restrict__ w10, const float* __restrict__ b10,
        float* __restrict__ fs5, Maps m) {
    int blk = blockIdx.x;   // b*30+a
    int a = blk % NACT, b = blk / NACT;
    int k = m.act_k[a];
    int spi = m.src_i[k], spj = m.src_j[k];

    __shared__ float buf[10400];            // Bs(8*260) | xs(32*260), reused as partials
    __shared__ float fs2s[8*33], fs3s[8*33];
    float* Bs = buf;
    float* xs = buf + 8*260;

    int t = threadIdx.x;
    int cg = t >> 5, s = t & 31;
    float acc[8][4];
    #pragma unroll
    for (int n=0;n<8;n++)
        #pragma unroll
        for (int i=0;i<4;i++) acc[n][i]=0.f;

    const float4* Bg4 = (const float4*)(B + (size_t)(b*NACT+a)*8*4096);
    const float* xb = x + (size_t)b*32*HW*HW;

    for (int ch = 0; ch < 16; ch++) {
        int l0 = ch*256;
        __syncthreads();
        #pragma unroll
        for (int q = 0; q < 2; q++) {
            int i4 = t + 256*q;
            int n = i4 >> 6, lq = i4 & 63;
            ((float4*)(Bs + n*260))[lq] = Bg4[n*1024 + (l0>>2) + lq];
        }
        #pragma unroll
        for (int q = 0; q < 8; q++) {
            int i4 = t + 256*q;
            int c = i4 >> 6, lq = i4 & 63;
            int l = l0 + lq*4;
            int y = l >> 6, xx = l & 63;
            float4 v = *(const float4*)(xb + (size_t)c*HW*HW + (size_t)(spi*64+y)*HW + spj*64 + xx);
            ((float4*)(xs + c*260))[lq] = v;
        }
        __syncthreads();
        #pragma unroll
        for (int st = 0; st < 2; st++) {
            int q = s + 32*st;
            float4 bv[8];
            #pragma unroll
            for (int n=0;n<8;n++) bv[n] = ((const float4*)(Bs + n*260))[q];
            #pragma unroll
            for (int i=0;i<4;i++) {
                float4 xv = ((const float4*)(xs + (cg*4+i)*260))[q];
                #pragma unroll
                for (int n=0;n<8;n++) {
                    acc[n][i] = fmaf(bv[n].x, xv.x, acc[n][i]);
                    acc[n][i] = fmaf(bv[n].y, xv.y, acc[n][i]);
                    acc[n][i] = fmaf(bv[n].z, xv.z, acc[n][i]);
                    acc[n][i] = fmaf(bv[n].w, xv.w, acc[n][i]);
                }
            }
        }
    }
    __syncthreads();
    #pragma unroll
    for (int n=0;n<8;n++)
        #pragma unroll
        for (int i=0;i<4;i++)
            buf[(n*32 + cg*4+i)*32 + s] = acc[n][i];
    __syncthreads();
    {
        int n = t >> 5, c = t & 31;
        float v = 0.f;
        #pragma unroll
        for (int ss=0; ss<32; ss++) v += buf[(n*32+c)*32 + ss];
        fs2s[n*33 + c] = v;
    }
    __syncthreads();
    {
        int o = t >> 5, c = t & 31;
        float v = b11[o];
        #pragma unroll
        for (int n=0;n<8;n++) v += w11[o*8+n]*fs2s[n*33+c];
        fs3s[o*33+c] = fmaxf(v, 0.f);
    }
    __syncthreads();
    {
        int cp = t >> 3, n = t & 7;
        float v = b10[cp];
        #pragma unroll
        for (int c=0;c<32;c++) v += w10[cp*32+c]*fs3s[n*33+c];
        fs5[((size_t)(b*64+k)*32 + cp)*8 + n] = fmaxf(v, 0.f);
    }
}

// ---------------- K5: fused fs6*g -> w31 -> BN -> relu -> +x -> out ---------------
__global__ __launch_bounds__(256) void k_out(
        const float* __restrict__ x, const float* __restrict__ B,
        const float* __restrict__ fs5, const float* __restrict__ g,
        const float* __restrict__ w31, const float* __restrict__ b31,
        const float* __restrict__ gamma, const float* __restrict__ beta,
        const float* __restrict__ mean, const float* __restrict__ var,
        float* __restrict__ out, Maps m) {
    int blk = blockIdx.x;   // b*64 + ij
    int rt = blockIdx.y;    // 0..3
    int ij = blk & 63, b = blk >> 6;
    int i = ij >> 3, j = ij & 7;
    int K = (i+1)*(j+1) - 1;
    int aK = m.aidx[K];
    __shared__ float Ms[256];
    __shared__ float sb[32], ss[32], sh[32];
    int t = threadIdx.x;
    {
        int o = t >> 3, n = t & 7;
        const float* f5 = fs5 + (size_t)(b*64+K)*32*8;
        const float* gg = g + (size_t)(b*64+K)*32;
        float v = 0.f;
        #pragma unroll
        for (int c=0;c<32;c++) v += w31[o*32+c]*gg[c]*f5[c*8+n];
        Ms[o*8+n] = v;
    }
    if (t < 32) {
        float sc = rsqrtf(var[t] + 1e-5f) * gamma[t];
        ss[t] = sc;
        sh[t] = beta[t] - mean[t]*sc;
        sb[t] = b31[t];
    }
    __syncthreads();
    int px = t & 63, og = t >> 6;
    float M[8][8], bo[8], so[8], ho[8];
    #pragma unroll
    for (int oo=0;oo<8;oo++) {
        int o = og*8+oo;
        bo[oo]=sb[o]; so[oo]=ss[o]; ho[oo]=sh[o];
        #pragma unroll
        for (int n=0;n<8;n++) M[oo][n] = Ms[o*8+n];
    }
    const float* Bp = B + (size_t)(b*NACT+aK)*8*4096;
    const float* xb = x + (size_t)b*32*HW*HW;
    float* ob = out + (size_t)b*32*HW*HW;
    for (int r = 0; r < 16; r++) {
        int y = rt*16 + r;
        int l = y*64 + px;
        int Y = i*64 + y, X = j*64 + px;
        float Bv[8];
        #pragma unroll
        for (int n=0;n<8;n++) Bv[n] = Bp[n*4096 + l];
        #pragma unroll
        for (int oo=0;oo<8;oo++) {
            int o = og*8+oo;
            float yv = bo[oo];
            #pragma unroll
            for (int n=0;n<8;n++) yv = fmaf(Bv[n], M[oo][n], yv);
            size_t ad = (size_t)o*HW*HW + (size_t)Y*HW + X;
            float res = fmaxf(yv*so[oo] + ho[oo], 0.f) + xb[ad];
            ob[ad] = res;
        }
    }
}

extern "C" void kernel_launch(void* const* d_in, const int* in_sizes, int n_in,
                              void* d_out, int out_size, void* d_ws, size_t ws_size,
                              hipStream_t stream) {
    const float* x    = (const float*)d_in[0];
    const float* w30  = (const float*)d_in[1];
    const float* b30  = (const float*)d_in[2];
    const float* w10  = (const float*)d_in[3];
    const float* b10  = (const float*)d_in[4];
    const float* w11  = (const float*)d_in[5];
    const float* b11  = (const float*)d_in[6];
    const float* w12a = (const float*)d_in[7];
    const float* b12a = (const float*)d_in[8];
    const float* w12b = (const float*)d_in[9];
    const float* b12b = (const float*)d_in[10];
    const float* w12c = (const float*)d_in[11];
    const float* b12c = (const float*)d_in[12];
    const float* w31  = (const float*)d_in[13];
    const float* b31  = (const float*)d_in[14];
    const float* gam  = (const float*)d_in[15];
    const float* bet  = (const float*)d_in[16];
    const float* mea  = (const float*)d_in[17];
    const float* var  = (const float*)d_in[18];
    float* out = (float*)d_out;

    float* ws  = (float*)d_ws;
    float* B   = ws;                       // 8*30*8*4096 = 7,864,320 floats
    float* fs5 = B + 7864320;              // 8*64*32*8   =   131,072
    float* fgw = fs5 + 131072;             // 8*64*32     =    16,384
    float* g   = fgw + 16384;              // 8*64*32     =    16,384

    static Maps m = make_maps();

    k_fg  <<<dim3(16384),  256, 0, stream>>>(x, fgw);
    k_g   <<<dim3(8),       64, 0, stream>>>(fgw, w12a, b12a, w12b, b12b, w12c, b12c, g);
    k_conv<<<dim3(240, 4), 256, 0, stream>>>(x, w30, b30, B, m);
    k_fs2 <<<dim3(240),    256, 0, stream>>>(x, B, w11, b11, w10, b10, fs5, m);
    k_out <<<dim3(512, 4), 256, 0, stream>>>(x, B, fs5, g, w31, b31, gam, bet, mea, var, out, m);
}

// Round 2
// 810.262 us; speedup vs baseline: 1.1077x; 1.1077x over previous
//
#include <hip/hip_runtime.h>
#include <math.h>
#include <stdint.h>

#define HW 512
#define NACT 30

struct Maps {
    int src_i[64];
    int src_j[64];
    int mask[64];
    int aidx[64];
    int act_k[NACT];
};

static Maps make_maps() {
    Maps m;
    for (int k = 0; k < 64; k++) { m.src_i[k]=0; m.src_j[k]=0; m.mask[k]=0; m.aidx[k]=-1; }
    for (int i = 1; i <= 8; i++)
        for (int j = 1; j <= 8; j++) {
            int k = i*j-1;
            m.src_i[k]=i-1; m.src_j[k]=j-1; m.mask[k]=1;
        }
    int cnt=0;
    for (int k=0;k<64;k++) if (m.mask[k]) { m.aidx[k]=cnt; if (cnt < NACT) m.act_k[cnt]=k; cnt++; }
    return m;
}

// ---------------- K0: zero fs2 accumulator ---------------------------------------
__global__ __launch_bounds__(256) void k_zero(float* __restrict__ p, int n) {
    int i = blockIdx.x*256 + threadIdx.x;
    if (i < n) p[i] = 0.f;
}

// ---------------- K1: per-patch means fg  (8,32,64 patches of 64x64) -------------
__global__ __launch_bounds__(256) void k_fg(const float* __restrict__ x, float* __restrict__ fgw) {
    int blk = blockIdx.x;            // ((b*32 + c)*64 + k)
    int k = blk & 63;
    int bc = blk >> 6;
    int c = bc & 31;
    int b = bc >> 5;
    int pi = k >> 3, pj = k & 7;
    const float* xp = x + (size_t)(b*32+c)*HW*HW;
    int t = threadIdx.x;
    float s = 0.f;
    #pragma unroll
    for (int ii = 0; ii < 4; ii++) {
        int idx4 = t + 256*ii;          // float4 index within patch, 0..1023
        int y = idx4 >> 4;
        int xx = (idx4 & 15) * 4;
        float4 v = *(const float4*)(xp + (size_t)(pi*64 + y)*HW + pj*64 + xx);
        s += v.x + v.y + v.z + v.w;
    }
    for (int off = 32; off > 0; off >>= 1) s += __shfl_down(s, off);
    __shared__ float p[4];
    if ((t & 63) == 0) p[t >> 6] = s;
    __syncthreads();
    if (t == 0) {
        float tot = p[0]+p[1]+p[2]+p[3];
        fgw[(b*64 + k)*32 + c] = tot * (1.0f/4096.0f);
    }
}

// ---------------- K2: tiny gating MLP -> g (8,64,32) ------------------------------
__global__ void k_g(const float* __restrict__ fgw,
                    const float* __restrict__ w12a, const float* __restrict__ b12a,
                    const float* __restrict__ w12b, const float* __restrict__ b12b,
                    const float* __restrict__ w12c, const float* __restrict__ b12c,
                    float* __restrict__ g) {
    int b = blockIdx.x;
    int c = threadIdx.x;
    if (c >= 32) return;
    float fg[64];
    #pragma unroll
    for (int k = 0; k < 64; k++) fg[k] = fgw[(b*64+k)*32 + c];
    float g1[8], g2[8];
    #pragma unroll
    for (int o = 0; o < 8; o++) {
        float v = b12a[o];
        #pragma unroll
        for (int k2 = 0; k2 < 64; k2++) v += w12a[o*64+k2]*fg[k2];
        g1[o] = fmaxf(v, 0.f);
    }
    #pragma unroll
    for (int o = 0; o < 8; o++) {
        float v = b12b[o];
        #pragma unroll
        for (int k2 = 0; k2 < 8; k2++) v += w12b[o*8+k2]*g1[k2];
        g2[o] = fmaxf(v, 0.f);
    }
    for (int o = 0; o < 64; o++) {
        float v = b12c[o];
        #pragma unroll
        for (int k2 = 0; k2 < 8; k2++) v += w12c[o*8+k2]*g2[k2];
        g[(b*64+o)*32 + c] = 1.f / (1.f + expf(-v));
    }
}

// ---------------- K3: per-patch 3x3 SAME conv + relu -> B (active blocks only) ----
// thread: col = t&63, tl = t>>6 owns output rows tl*4 .. tl*4+3 (within 16-row tile)
__global__ __launch_bounds__(256) void k_conv(
        const float* __restrict__ x, const float* __restrict__ w30,
        const float* __restrict__ b30, float* __restrict__ B, Maps m) {
    int blk = blockIdx.x;         // b*30 + a
    int rt = blockIdx.y;          // 0..3 row tile of 16
    int a = blk % NACT, b = blk / NACT;
    int k = m.act_k[a];
    int spi = m.src_i[k], spj = m.src_j[k];
    int r0 = rt*16;

    __shared__ float wl2[32*9*8];   // [c][dydx][n] -> 8 n contiguous
    __shared__ float xs[8*18*66];   // [cc][row(18)][col(66)]

    int t = threadIdx.x;
    for (int idx = t; idx < 2304; idx += 256) {
        int c = idx / 72;
        int rem = idx - c*72;
        int dydx = rem >> 3;
        int n = rem & 7;
        wl2[idx] = w30[(n*32 + c)*9 + dydx];
    }

    int col = t & 63, tl = t >> 6;
    float acc[4][8];
    #pragma unroll
    for (int rr=0; rr<4; rr++)
        #pragma unroll
        for (int n=0;n<8;n++) acc[rr][n]=0.f;

    const float* xb = x + (size_t)b*32*HW*HW;

    for (int c0 = 0; c0 < 32; c0 += 8) {
        __syncthreads();
        for (int idx = t; idx < 8*18*66; idx += 256) {
            int cc = idx / (18*66);
            int rem = idx - cc*(18*66);
            int r = rem / 66;
            int ccol = rem - r*66;
            int pr = r0 - 1 + r;
            int pc = ccol - 1;
            float v = 0.f;
            if (pr >= 0 && pr < 64 && pc >= 0 && pc < 64)
                v = xb[(size_t)(c0+cc)*HW*HW + (size_t)(spi*64+pr)*HW + spj*64 + pc];
            xs[idx] = v;
        }
        __syncthreads();
        for (int cc = 0; cc < 8; cc++) {
            // 18 distinct x values cover all (rr,dy,dx) for this thread
            const float* xrow = xs + cc*1188 + (tl*4)*66 + col;
            float xv[6][3];
            #pragma unroll
            for (int r6 = 0; r6 < 6; r6++)
                #pragma unroll
                for (int d = 0; d < 3; d++)
                    xv[r6][d] = xrow[r6*66 + d];
            const float* wb = wl2 + (c0+cc)*72;
            #pragma unroll
            for (int dy = 0; dy < 3; dy++) {
                #pragma unroll
                for (int dx = 0; dx < 3; dx++) {
                    float4 wa0 = *(const float4*)(wb + (dy*3+dx)*8);
                    float4 wa1 = *(const float4*)(wb + (dy*3+dx)*8 + 4);
                    #pragma unroll
                    for (int rr = 0; rr < 4; rr++) {
                        float xvv = xv[rr+dy][dx];
                        acc[rr][0] = fmaf(xvv, wa0.x, acc[rr][0]);
                        acc[rr][1] = fmaf(xvv, wa0.y, acc[rr][1]);
                        acc[rr][2] = fmaf(xvv, wa0.z, acc[rr][2]);
                        acc[rr][3] = fmaf(xvv, wa0.w, acc[rr][3]);
                        acc[rr][4] = fmaf(xvv, wa1.x, acc[rr][4]);
                        acc[rr][5] = fmaf(xvv, wa1.y, acc[rr][5]);
                        acc[rr][6] = fmaf(xvv, wa1.z, acc[rr][6]);
                        acc[rr][7] = fmaf(xvv, wa1.w, acc[rr][7]);
                    }
                }
            }
        }
    }
    float* Bp = B + (size_t)(b*NACT+a)*8*4096;
    #pragma unroll
    for (int rr=0; rr<4; rr++) {
        int y = r0 + tl*4 + rr;
        #pragma unroll
        for (int n=0;n<8;n++)
            Bp[n*4096 + y*64 + col] = fmaxf(acc[rr][n] + b30[n], 0.f);
    }
}

// ---------------- K4a: partial fs2 = B @ fs^T over L-chunk, atomic accumulate ----
__global__ __launch_bounds__(256) void k_fs2a(
        const float* __restrict__ x, const float* __restrict__ B,
        float* __restrict__ fs2g, Maps m) {
    int blk = blockIdx.x;   // b*30+a
    int rt = blockIdx.y;    // 0..3 -> chunks [rt*4, rt*4+4)
    int a = blk % NACT, b = blk / NACT;
    int k = m.act_k[a];
    int spi = m.src_i[k], spj = m.src_j[k];

    __shared__ float buf[10400];            // Bs(8*260) | xs(32*260), reused as partials
    float* Bs = buf;
    float* xs = buf + 8*260;

    int t = threadIdx.x;
    int cg = t >> 5, s = t & 31;
    float acc[8][4];
    #pragma unroll
    for (int n=0;n<8;n++)
        #pragma unroll
        for (int i=0;i<4;i++) acc[n][i]=0.f;

    const float4* Bg4 = (const float4*)(B + (size_t)(b*NACT+a)*8*4096);
    const float* xb = x + (size_t)b*32*HW*HW;

    for (int ch = rt*4; ch < rt*4+4; ch++) {
        int l0 = ch*256;
        __syncthreads();
        #pragma unroll
        for (int q = 0; q < 2; q++) {
            int i4 = t + 256*q;
            int n = i4 >> 6, lq = i4 & 63;
            ((float4*)(Bs + n*260))[lq] = Bg4[n*1024 + (l0>>2) + lq];
        }
        #pragma unroll
        for (int q = 0; q < 8; q++) {
            int i4 = t + 256*q;
            int c = i4 >> 6, lq = i4 & 63;
            int l = l0 + lq*4;
            int y = l >> 6, xx = l & 63;
            float4 v = *(const float4*)(xb + (size_t)c*HW*HW + (size_t)(spi*64+y)*HW + spj*64 + xx);
            ((float4*)(xs + c*260))[lq] = v;
        }
        __syncthreads();
        #pragma unroll
        for (int st = 0; st < 2; st++) {
            int q = s + 32*st;
            float4 bv[8];
            #pragma unroll
            for (int n=0;n<8;n++) bv[n] = ((const float4*)(Bs + n*260))[q];
            #pragma unroll
            for (int i=0;i<4;i++) {
                float4 xv = ((const float4*)(xs + (cg*4+i)*260))[q];
                #pragma unroll
                for (int n=0;n<8;n++) {
                    acc[n][i] = fmaf(bv[n].x, xv.x, acc[n][i]);
                    acc[n][i] = fmaf(bv[n].y, xv.y, acc[n][i]);
                    acc[n][i] = fmaf(bv[n].z, xv.z, acc[n][i]);
                    acc[n][i] = fmaf(bv[n].w, xv.w, acc[n][i]);
                }
            }
        }
    }
    __syncthreads();
    #pragma unroll
    for (int n=0;n<8;n++)
        #pragma unroll
        for (int i=0;i<4;i++)
            buf[(n*32 + cg*4+i)*32 + s] = acc[n][i];
    __syncthreads();
    {
        int n = t >> 5, c = t & 31;
        float v = 0.f;
        #pragma unroll
        for (int ss=0; ss<32; ss++) v += buf[(n*32+c)*32 + ss];
        atomicAdd(&fs2g[(size_t)(b*NACT+a)*256 + n*32 + c], v);
    }
}

// ---------------- K4b: fs2 -> fs3 -> fs5 -----------------------------------------
__global__ __launch_bounds__(256) void k_fs3(
        const float* __restrict__ fs2g,
        const float* __restrict__ w11, const float* __restrict__ b11,
        const float* __restrict__ w10, const float* __restrict__ b10,
        float* __restrict__ fs5, Maps m) {
    int blk = blockIdx.x;   // b*30+a
    int a = blk % NACT, b = blk / NACT;
    int k = m.act_k[a];
    __shared__ float fs2s[8*33], fs3s[8*33];
    int t = threadIdx.x;
    {
        int n = t >> 5, c = t & 31;
        fs2s[n*33+c] = fs2g[(size_t)(b*NACT+a)*256 + n*32 + c];
    }
    __syncthreads();
    {
        int o = t >> 5, c = t & 31;
        float v = b11[o];
        #pragma unroll
        for (int n=0;n<8;n++) v += w11[o*8+n]*fs2s[n*33+c];
        fs3s[o*33+c] = fmaxf(v, 0.f);
    }
    __syncthreads();
    {
        int cp = t >> 3, n = t & 7;
        float v = b10[cp];
        #pragma unroll
        for (int c=0;c<32;c++) v += w10[cp*32+c]*fs3s[n*33+c];
        fs5[((size_t)(b*64+k)*32 + cp)*8 + n] = fmaxf(v, 0.f);
    }
}

// ---------------- K5: fused fs6*g -> w31 -> BN -> relu -> +x -> out ---------------
// thread: r = t>>4 (row within 16-row tile), q = t&15 (4-px group); 32 o per thread
__global__ __launch_bounds__(256) void k_out(
        const float* __restrict__ x, const float* __restrict__ B,
        const float* __restrict__ fs5, const float* __restrict__ g,
        const float* __restrict__ w31, const float* __restrict__ b31,
        const float* __restrict__ gamma, const float* __restrict__ beta,
        const float* __restrict__ mean, const float* __restrict__ var,
        float* __restrict__ out, Maps m) {
    int blk = blockIdx.x;   // b*64 + ij
    int rt = blockIdx.y;    // 0..3
    int ij = blk & 63, b = blk >> 6;
    int i = ij >> 3, j = ij & 7;
    int K = (i+1)*(j+1) - 1;
    int aK = m.aidx[K];
    __shared__ float Ms[256];        // [o][n]
    __shared__ float ss2[32], sh2[32];
    int t = threadIdx.x;
    {
        int o = t >> 3, n = t & 7;
        const float* f5 = fs5 + (size_t)(b*64+K)*32*8;
        const float* gg = g + (size_t)(b*64+K)*32;
        float v = 0.f;
        #pragma unroll
        for (int c=0;c<32;c++) v += w31[o*32+c]*gg[c]*f5[c*8+n];
        Ms[o*8+n] = v;
    }
    if (t < 32) {
        float sc = rsqrtf(var[t] + 1e-5f) * gamma[t];
        ss2[t] = sc;
        sh2[t] = (b31[t] - mean[t])*sc + beta[t];   // fold conv bias + BN shift
    }
    __syncthreads();

    int r = t >> 4, q = t & 15;
    int y = rt*16 + r;
    int Y = i*64 + y;
    int X = j*64 + q*4;
    const float* Bp = B + (size_t)(b*NACT+aK)*8*4096 + y*64 + q*4;
    const float* xb = x + (size_t)b*32*HW*HW + (size_t)Y*HW + X;
    float* ob = out + (size_t)b*32*HW*HW + (size_t)Y*HW + X;

    float4 Bv[8];
    #pragma unroll
    for (int n=0;n<8;n++) Bv[n] = *(const float4*)(Bp + n*4096);

    #pragma unroll 4
    for (int o = 0; o < 32; o++) {
        float4 Ma = *(const float4*)(Ms + o*8);
        float4 Mb = *(const float4*)(Ms + o*8 + 4);
        float so = ss2[o], ho = sh2[o];
        float4 xv = *(const float4*)(xb + (size_t)o*HW*HW);
        float4 yv;
        yv.x = Bv[0].x*Ma.x + Bv[1].x*Ma.y + Bv[2].x*Ma.z + Bv[3].x*Ma.w
             + Bv[4].x*Mb.x + Bv[5].x*Mb.y + Bv[6].x*Mb.z + Bv[7].x*Mb.w;
        yv.y = Bv[0].y*Ma.x + Bv[1].y*Ma.y + Bv[2].y*Ma.z + Bv[3].y*Ma.w
             + Bv[4].y*Mb.x + Bv[5].y*Mb.y + Bv[6].y*Mb.z + Bv[7].y*Mb.w;
        yv.z = Bv[0].z*Ma.x + Bv[1].z*Ma.y + Bv[2].z*Ma.z + Bv[3].z*Ma.w
             + Bv[4].z*Mb.x + Bv[5].z*Mb.y + Bv[6].z*Mb.z + Bv[7].z*Mb.w;
        yv.w = Bv[0].w*Ma.x + Bv[1].w*Ma.y + Bv[2].w*Ma.z + Bv[3].w*Ma.w
             + Bv[4].w*Mb.x + Bv[5].w*Mb.y + Bv[6].w*Mb.z + Bv[7].w*Mb.w;
        float4 res;
        res.x = fmaxf(yv.x*so + ho, 0.f) + xv.x;
        res.y = fmaxf(yv.y*so + ho, 0.f) + xv.y;
        res.z = fmaxf(yv.z*so + ho, 0.f) + xv.z;
        res.w = fmaxf(yv.w*so + ho, 0.f) + xv.w;
        *(float4*)(ob + (size_t)o*HW*HW) = res;
    }
}

extern "C" void kernel_launch(void* const* d_in, const int* in_sizes, int n_in,
                              void* d_out, int out_size, void* d_ws, size_t ws_size,
                              hipStream_t stream) {
    const float* x    = (const float*)d_in[0];
    const float* w30  = (const float*)d_in[1];
    const float* b30  = (const float*)d_in[2];
    const float* w10  = (const float*)d_in[3];
    const float* b10  = (const float*)d_in[4];
    const float* w11  = (const float*)d_in[5];
    const float* b11  = (const float*)d_in[6];
    const float* w12a = (const float*)d_in[7];
    const float* b12a = (const float*)d_in[8];
    const float* w12b = (const float*)d_in[9];
    const float* b12b = (const float*)d_in[10];
    const float* w12c = (const float*)d_in[11];
    const float* b12c = (const float*)d_in[12];
    const float* w31  = (const float*)d_in[13];
    const float* b31  = (const float*)d_in[14];
    const float* gam  = (const float*)d_in[15];
    const float* bet  = (const float*)d_in[16];
    const float* mea  = (const float*)d_in[17];
    const float* var  = (const float*)d_in[18];
    float* out = (float*)d_out;

    float* ws   = (float*)d_ws;
    float* B    = ws;                       // 8*30*8*4096 = 7,864,320 floats
    float* fs5  = B + 7864320;              // 8*64*32*8   =   131,072
    float* fgw  = fs5 + 131072;             // 8*64*32     =    16,384
    float* g    = fgw + 16384;              // 8*64*32     =    16,384
    float* fs2g = g + 16384;                // 8*30*256    =    61,440

    static Maps m = make_maps();

    k_zero<<<dim3(240),    256, 0, stream>>>(fs2g, 61440);
    k_fg  <<<dim3(16384),  256, 0, stream>>>(x, fgw);
    k_g   <<<dim3(8),       64, 0, stream>>>(fgw, w12a, b12a, w12b, b12b, w12c, b12c, g);
    k_conv<<<dim3(240, 4), 256, 0, stream>>>(x, w30, b30, B, m);
    k_fs2a<<<dim3(240, 4), 256, 0, stream>>>(x, B, fs2g, m);
    k_fs3 <<<dim3(240),    256, 0, stream>>>(fs2g, w11, b11, w10, b10, fs5, m);
    k_out <<<dim3(512, 4), 256, 0, stream>>>(x, B, fs5, g, w31, b31, gam, bet, mea, var, out, m);
}